// Round 12
// baseline (306.787 us; speedup 1.0000x reference)
//
#include <hip/hip_runtime.h>

// Problem constants
#define NB 8
#define NC 128
#define NH 64
#define NW 64
#define HEADS 4
#define HP 32
#define WP 32
#define NTOK 1024     // HP*WP
#define TOPK 32
#define HDIM 32

typedef float v2f __attribute__((ext_vector_type(2)));

// ---------------------------------------------------------------
// bf16 helpers (round-to-nearest-even)
__device__ __forceinline__ unsigned bf16r(float f) {
  unsigned u = __float_as_uint(f);
  return (u + 0x7FFFu + ((u >> 16) & 1u)) >> 16;
}

// monotone float->uint map (order-preserving) and inverse
__device__ __forceinline__ unsigned fmap(float f) {
  unsigned u = __float_as_uint(f);
  return u ^ ((unsigned)((int)u >> 31) | 0x80000000u);
}
__device__ __forceinline__ float funmap(unsigned k) {
  unsigned uo = k ^ ((unsigned)((int)(~k) >> 31) | 0x80000000u);
  return __uint_as_float(uo);
}

__device__ __forceinline__ v2f bfpair(unsigned w) {
  v2f r;
  r.x = __uint_as_float(w << 16);
  r.y = __uint_as_float(w & 0xFFFF0000u);
  return r;
}

// DPP wave64 max-reduce on unsigned; result broadcast via readlane(63)
__device__ __forceinline__ unsigned wave_maxu(unsigned v) {
#define ST(ctrl)                                                                     \
  {                                                                                  \
    unsigned o = (unsigned)__builtin_amdgcn_update_dpp(0, (int)v, ctrl, 0xF, 0xF, true); \
    v = v > o ? v : o;                                                               \
  }
  ST(0xB1)   // quad_perm [1,0,3,2]
  ST(0x4E)   // quad_perm [2,3,0,1]
  ST(0x141)  // row_half_mirror
  ST(0x140)  // row_mirror
  ST(0x142)  // row_bcast:15
  ST(0x143)  // row_bcast:31
#undef ST
  return (unsigned)__builtin_amdgcn_readlane((int)v, 63);
}

// DPP wave64 float sum-reduce; result broadcast via readlane(63)
__device__ __forceinline__ float wave_sumf(float v) {
#define STA(ctrl)                                                                    \
  v += __int_as_float(__builtin_amdgcn_update_dpp(0, __float_as_int(v), ctrl, 0xF, 0xF, true));
  STA(0xB1)
  STA(0x4E)
  STA(0x141)
  STA(0x140)
  STA(0x142)
  STA(0x143)
#undef STA
  return __int_as_float(__builtin_amdgcn_readlane(__float_as_int(v), 63));
}

// DPP wave64 inclusive prefix-sum on unsigned. Safe for packed 16+16 fields.
__device__ __forceinline__ unsigned wave_iprefix(unsigned v, int lane) {
#define SH(ctrl)                                                                     \
  v += (unsigned)__builtin_amdgcn_update_dpp(0, (int)v, ctrl, 0xF, 0xF, true);
  SH(0x111)  // row_shr:1
  SH(0x112)  // row_shr:2
  SH(0x114)  // row_shr:4
  SH(0x118)  // row_shr:8
#undef SH
  unsigned r0 = (unsigned)__builtin_amdgcn_readlane((int)v, 15);
  unsigned r1 = (unsigned)__builtin_amdgcn_readlane((int)v, 31);
  unsigned r2 = (unsigned)__builtin_amdgcn_readlane((int)v, 47);
  v += (lane >= 16) ? r0 : 0u;
  v += (lane >= 32) ? r1 : 0u;
  v += (lane >= 48) ? r2 : 0u;
  return v;
}

// ---------------------------------------------------------------
// avg pool 2x2 on x and y
__global__ void k_pool(const float* __restrict__ x, const float* __restrict__ y,
                       float* __restrict__ xp, float* __restrict__ yp) {
  int idx = blockIdx.x * 256 + threadIdx.x;
  const int total = NB * NC * HP * WP; // 1,048,576
  if (idx >= 2 * total) return;
  bool isY = idx >= total;
  int i = isY ? idx - total : idx;
  int pw = i & 31, ph = (i >> 5) & 31, bc = i >> 10;
  const float* src = (isY ? y : x) + ((size_t)bc * 64 + ph * 2) * 64 + pw * 2;
  float v = 0.25f * (src[0] + src[1] + src[64] + src[65]);
  (isY ? yp : xp)[i] = v;
}

// ---------------------------------------------------------------
// fused q path: 1x1 conv (4 ch/thread, wave-uniform weights) -> LDS tile ->
// depthwise 3x3. block = 1024 threads (one 32x32 image), grid = 8b x 32 quads.
__launch_bounds__(1024, 2)
__global__ void k_qpath(const float* __restrict__ xp, const float* __restrict__ w1,
                        const float* __restrict__ b1, const float* __restrict__ w2,
                        const float* __restrict__ b2, float* __restrict__ qbuf) {
  __shared__ float cls[4][1024];
  int px = threadIdx.x;
  int q = blockIdx.x & 31;   // channel quad (4 channels)
  int b = blockIdx.x >> 5;
  const float* ip = xp + (size_t)b * NC * NTOK + px;
  const float* wp = w1 + q * 4 * NC;
  float acc[4];
#pragma unroll
  for (int i = 0; i < 4; i++) acc[i] = b1[q * 4 + i];
  for (int ci = 0; ci < NC; ci++) {
    float mv = ip[ci * NTOK];
#pragma unroll
    for (int i = 0; i < 4; i++) acc[i] = fmaf(wp[i * NC + ci], mv, acc[i]);
  }
#pragma unroll
  for (int i = 0; i < 4; i++) cls[i][px] = acc[i];
  __syncthreads();
  int pw = px & 31, ph = px >> 5;
#pragma unroll
  for (int i = 0; i < 4; i++) {
    int c = q * 4 + i;
    const float* wq = w2 + c * 9;
    float a = b2[c];
#pragma unroll
    for (int ky = 0; ky < 3; ky++) {
      int ih = ph + ky - 1;
      if (ih < 0 || ih > 31) continue;
#pragma unroll
      for (int kx = 0; kx < 3; kx++) {
        int iw = pw + kx - 1;
        if (iw < 0 || iw > 31) continue;
        a = fmaf(wq[ky * 3 + kx], cls[i][ih * 32 + iw], a);
      }
    }
    qbuf[((size_t)b * NC + c) * NTOK + px] = a;
  }
}

// ---------------------------------------------------------------
// fused kv path: 1x1 conv (4 ch/thread) -> LDS tile -> grouped 3x3 (2-ch
// groups are self-contained in a 4-ch quad) -> bf16 K / bf16 V.
// block = 1024 threads, grid = 8b x 64 quads.
__launch_bounds__(1024, 2)
__global__ void k_kvpath(const float* __restrict__ yp, const float* __restrict__ w1,
                         const float* __restrict__ b1, const float* __restrict__ w2,
                         const float* __restrict__ b2, unsigned short* __restrict__ kbf,
                         unsigned short* __restrict__ vbf) {
  __shared__ float cls[4][1024];
  int px = threadIdx.x;
  int q = blockIdx.x & 63;   // channel quad of the 256 kv1 channels
  int b = blockIdx.x >> 6;
  const float* ip = yp + (size_t)b * NC * NTOK + px;
  const float* wp = w1 + q * 4 * NC;
  float acc[4];
#pragma unroll
  for (int i = 0; i < 4; i++) acc[i] = b1[q * 4 + i];
  for (int ci = 0; ci < NC; ci++) {
    float mv = ip[ci * NTOK];
#pragma unroll
    for (int i = 0; i < 4; i++) acc[i] = fmaf(wp[i * NC + ci], mv, acc[i]);
  }
#pragma unroll
  for (int i = 0; i < 4; i++) cls[i][px] = acc[i];
  __syncthreads();
  int pw = px & 31, ph = px >> 5;
#pragma unroll
  for (int i = 0; i < 4; i++) {
    int o = q * 4 + i;       // kv1/kv2 channel 0..255
    int l0 = i & ~1;         // local index of the group's first input channel
    const float* wq = w2 + o * 18; // [2][3][3]
    float a = b2[o];
#pragma unroll
    for (int ky = 0; ky < 3; ky++) {
      int ih = ph + ky - 1;
      if (ih < 0 || ih > 31) continue;
#pragma unroll
      for (int kx = 0; kx < 3; kx++) {
        int iw = pw + kx - 1;
        if (iw < 0 || iw > 31) continue;
        a = fmaf(wq[ky * 3 + kx], cls[l0][ih * 32 + iw], a);
        a = fmaf(wq[9 + ky * 3 + kx], cls[l0 + 1][ih * 32 + iw], a);
      }
    }
    unsigned short bv = (unsigned short)bf16r(a);
    if (o < 128) {
      kbf[((size_t)b * NC + o) * NTOK + px] = bv;
    } else {
      int c = o - 128;
      int h = c >> 5, d = c & 31;
      vbf[(((size_t)b * HEADS + h) * NTOK + px) * HDIM + d] = bv;
    }
  }
}

// ---------------------------------------------------------------
// attention v9: 4 rows per wave (K staging/LDS reads/unpack amortized),
// rel fused at pack time (no prefetch register pressure), early-exit bsearch.
// grid: 1024 = 32 chunks x 4 h x 8 b; block 512 (8 waves), 4 rows per wave.
__launch_bounds__(512, 2)
__global__ void k_attn(const float* __restrict__ qbuf, const unsigned short* __restrict__ kbf,
                       const unsigned short* __restrict__ vbf, const float* __restrict__ rel,
                       const float* __restrict__ temp, float* __restrict__ att) {
  __shared__ __align__(16) unsigned ksh[16384];  // bf16 K [d][n], 64KB
  __shared__ __align__(16) unsigned cbuf[8 * 64]; // per-wave 32x(key,token), 2KB

  int bid = blockIdx.x;
  int chunk = bid & 31;
  int h = (bid >> 5) & 3;
  int b = bid >> 7;
  int tid = threadIdx.x;
  int lane = tid & 63;
  int wave = __builtin_amdgcn_readfirstlane(tid >> 6); // 0..7, uniform

  // stage K (already bf16 in global): 8192 uint2 total, 512 threads x 16
  const uint2* kg = (const uint2*)(kbf + ((size_t)b * NC + h * HDIM) * NTOK);
  uint2* kl = (uint2*)ksh;
#pragma unroll
  for (int i = 0; i < 16; i++) kl[tid + i * 512] = kg[tid + i * 512];
  __syncthreads();

  const float tmpr = temp[h];
  const uint2* k2 = (const uint2*)ksh;
  const unsigned short* vb = vbf + ((size_t)(b * HEADS + h)) * NTOK * HDIM;
  int vlane = lane & 31;
  unsigned* row_lds = cbuf + wave * 64; // 32 entries x 8B, private per wave

  int qbase = chunk * 32 + wave * 4;

  // acc init = 0 (rel fused later at pack time)
  v2f acc2[4][8];
#pragma unroll
  for (int r = 0; r < 4; r++)
#pragma unroll
    for (int i = 0; i < 8; i++) acc2[r][i] = (v2f){0.f, 0.f};

  // logits: acc += q_d * K[d][j]; 4 rows share each K read/unpack
  const float* q0 = qbuf + ((size_t)b * NC + h * HDIM) * NTOK + qbase;
#pragma unroll 4
  for (int d = 0; d < 32; d++) {
    float4 qv = *(const float4*)&q0[d * NTOK];
#pragma unroll
    for (int i = 0; i < 4; i++) {
      uint2 kw = k2[d * 256 + i * 64 + lane];
      v2f klo = bfpair(kw.x);
      v2f khi = bfpair(kw.y);
      v2f q0s = {qv.x, qv.x}, q1s = {qv.y, qv.y}, q2s = {qv.z, qv.z}, q3s = {qv.w, qv.w};
      acc2[0][i * 2 + 0] = __builtin_elementwise_fma(q0s, klo, acc2[0][i * 2 + 0]);
      acc2[0][i * 2 + 1] = __builtin_elementwise_fma(q0s, khi, acc2[0][i * 2 + 1]);
      acc2[1][i * 2 + 0] = __builtin_elementwise_fma(q1s, klo, acc2[1][i * 2 + 0]);
      acc2[1][i * 2 + 1] = __builtin_elementwise_fma(q1s, khi, acc2[1][i * 2 + 1]);
      acc2[2][i * 2 + 0] = __builtin_elementwise_fma(q2s, klo, acc2[2][i * 2 + 0]);
      acc2[2][i * 2 + 1] = __builtin_elementwise_fma(q2s, khi, acc2[2][i * 2 + 1]);
      acc2[3][i * 2 + 0] = __builtin_elementwise_fma(q3s, klo, acc2[3][i * 2 + 0]);
      acc2[3][i * 2 + 1] = __builtin_elementwise_fma(q3s, khi, acc2[3][i * 2 + 1]);
    }
  }

  // pack keys row-by-row, fusing rel (acc2[r] dies as kk[r] is born)
  const float4* relp = (const float4*)(rel + (((size_t)b * HEADS + h) * NTOK + qbase) * NTOK);
  unsigned kk[4][16];
#pragma unroll
  for (int r = 0; r < 4; r++) {
#pragma unroll
    for (int i = 0; i < 4; i++) {
      float4 rv = relp[r * 256 + i * 64 + lane];
      kk[r][i * 4 + 0] = fmap(fmaf(tmpr, acc2[r][i * 2 + 0].x, rv.x));
      kk[r][i * 4 + 1] = fmap(fmaf(tmpr, acc2[r][i * 2 + 0].y, rv.y));
      kk[r][i * 4 + 2] = fmap(fmaf(tmpr, acc2[r][i * 2 + 1].x, rv.z));
      kk[r][i * 4 + 3] = fmap(fmaf(tmpr, acc2[r][i * 2 + 1].y, rv.w));
    }
  }

  // wave max per row (bsearch upper bound + softmax max)
  unsigned M[4];
#pragma unroll
  for (int r = 0; r < 4; r++) {
    unsigned mx = kk[r][0];
#pragma unroll
    for (int e = 1; e < 16; e++) mx = mx > kk[r][e] ? mx : kk[r][e];
    M[r] = wave_maxu(mx);
  }

  // early-exit binary search (4 rows interleaved); cap 32 -> exact-tie fallback
  unsigned lo0 = 0u, hi0 = M[0], lo1 = 0u, hi1 = M[1];
  unsigned lo2 = 0u, hi2 = M[2], lo3 = 0u, hi3 = M[3];
  unsigned T0x = 0u, T1x = 0u, T2x = 0u, T3x = 0u;
  bool d0 = false, d1 = false, d2 = false, d3 = false;
#pragma unroll 1
  for (int it = 0; it < 32; it++) {
    if (d0 && d1 && d2 && d3) break;
    if (!d0) {
      unsigned mid = lo0 + ((hi0 - lo0) >> 1);
      int c = 0;
#pragma unroll
      for (int e = 0; e < 16; e++) c += (int)__popcll(__ballot(kk[0][e] > mid));
      if (c >= TOPK) lo0 = mid; else hi0 = mid;
      if (c == TOPK) { T0x = mid; d0 = true; }
    }
    if (!d1) {
      unsigned mid = lo1 + ((hi1 - lo1) >> 1);
      int c = 0;
#pragma unroll
      for (int e = 0; e < 16; e++) c += (int)__popcll(__ballot(kk[1][e] > mid));
      if (c >= TOPK) lo1 = mid; else hi1 = mid;
      if (c == TOPK) { T1x = mid; d1 = true; }
    }
    if (!d2) {
      unsigned mid = lo2 + ((hi2 - lo2) >> 1);
      int c = 0;
#pragma unroll
      for (int e = 0; e < 16; e++) c += (int)__popcll(__ballot(kk[2][e] > mid));
      if (c >= TOPK) lo2 = mid; else hi2 = mid;
      if (c == TOPK) { T2x = mid; d2 = true; }
    }
    if (!d3) {
      unsigned mid = lo3 + ((hi3 - lo3) >> 1);
      int c = 0;
#pragma unroll
      for (int e = 0; e < 16; e++) c += (int)__popcll(__ballot(kk[3][e] > mid));
      if (c >= TOPK) lo3 = mid; else hi3 = mid;
      if (c == TOPK) { T3x = mid; d3 = true; }
    }
  }
  unsigned T[4];
  T[0] = d0 ? T0x : hi0;
  T[1] = d1 ? T1x : hi1;
  T[2] = d2 ? T2x : hi2;
  T[3] = d3 ? T3x : hi3;

  // per-row: tie handling, compaction, softmax + V gather (r unrolled -> static)
#pragma unroll
  for (int r = 0; r < 4; r++) {
    unsigned gtc = 0, tq = 0;
#pragma unroll
    for (int e = 0; e < 16; e++) {
      gtc += (kk[r][e] > T[r]) ? 1u : 0u;
      tq += (kk[r][e] == T[r]) ? 1u : 0u;
    }
    unsigned packed = gtc | (tq << 16);
    unsigned incl = wave_iprefix(packed, lane);
    unsigned tot = (unsigned)__builtin_amdgcn_readlane((int)incl, 63);
    unsigned n_gt = tot & 0xFFFFu;
    unsigned tie_pfx = (incl >> 16) - tq;
    unsigned extras = (unsigned)TOPK - n_gt; // 0 on early-exit rows
    int el = (int)extras - (int)tie_pfx;
    el = el < 0 ? 0 : el;
    el = el > (int)tq ? (int)tq : el;
    unsigned sc = gtc + (unsigned)el;
    unsigned wbase = wave_iprefix(sc, lane) - sc;

    unsigned wp = wbase, tr = tie_pfx;
#pragma unroll
    for (int e = 0; e < 16; e++) {
      bool gt = kk[r][e] > T[r];
      bool eq = (kk[r][e] == T[r]);
      bool take = gt || (eq && (tr < extras));
      tr += eq ? 1u : 0u;
      if (take) {
        ((uint2*)row_lds)[wp] = make_uint2(kk[r][e], (unsigned)((e >> 2) * 256 + lane * 4 + (e & 3)));
        wp++;
      }
    }

    // parallel softmax over the 32 entries (lanes 0..31) + pipelined V gather
    uint2 ent = ((const uint2*)row_lds)[vlane];
    float fv = funmap(ent.x);
    float mv = funmap(M[r]);
    float e_ = __expf(fv - mv);
    e_ = (lane < TOPK) ? e_ : 0.f;
    float se = wave_sumf(e_);

    float oacc = 0.f;
#pragma unroll
    for (int t = 0; t < TOPK; t++) {
      float es = __int_as_float(__builtin_amdgcn_readlane(__float_as_int(e_), t));
      int tok = __builtin_amdgcn_readlane((int)ent.y, t);
      float vv = __uint_as_float((unsigned)vb[(size_t)tok * HDIM + vlane] << 16);
      oacc = fmaf(es, vv, oacc);
    }

    if (lane < HDIM) {
      att[((size_t)b * NC + h * HDIM + lane) * NTOK + (qbase + r)] = oacc / se;
    }
  }
}

// ---------------------------------------------------------------
// bilinear 2x upsample weights (jax scale_and_translate semantics)
__device__ __forceinline__ void bil(int i, int& j0, int& j1, float& wa, float& wb) {
  if (i & 1) {
    j0 = i >> 1; j1 = j0 + 1; wa = 0.75f; wb = 0.25f;
    if (j1 > 31) { j1 = 31; wa = 1.f; wb = 0.f; }
  } else {
    j0 = (i >> 1) - 1; j1 = j0 + 1; wa = 0.25f; wb = 0.75f;
    if (j0 < 0) { j0 = 0; wa = 0.f; wb = 1.f; }
  }
}

// mid = lepe(x) + upsample(att) ; (B,128,64,64)
__global__ void k_mid(const float* __restrict__ x, const float* __restrict__ lepe_w,
                      const float* __restrict__ lepe_b, const float* __restrict__ att,
                      float* __restrict__ mid) {
  int t = blockIdx.x * 256 + threadIdx.x;
  if (t >= NB * NC * NH * NW) return;
  int w = t & 63;
  int h0 = (t >> 6) & 63;
  int bc = t >> 12;
  int c = bc & 127;
  const float* xp = x + (size_t)bc * (NH * NW);
  const float* wp = lepe_w + c * 25;
  float acc = lepe_b[c];
#pragma unroll
  for (int ky = 0; ky < 5; ky++) {
    int ih = h0 + ky - 2;
    if (ih < 0 || ih > 63) continue;
#pragma unroll
    for (int kx = 0; kx < 5; kx++) {
      int iw = w + kx - 2;
      if (iw < 0 || iw > 63) continue;
      acc = fmaf(wp[ky * 5 + kx], xp[ih * 64 + iw], acc);
    }
  }
  int jh0, jh1, jw0, jw1;
  float wha, whb, wwa, wwb;
  bil(h0, jh0, jh1, wha, whb);
  bil(w, jw0, jw1, wwa, wwb);
  const float* ap = att + (size_t)bc * NTOK;
  float up = wha * (wwa * ap[jh0 * 32 + jw0] + wwb * ap[jh0 * 32 + jw1]) +
             whb * (wwa * ap[jh1 * 32 + jw0] + wwb * ap[jh1 * 32 + jw1]);
  mid[t] = acc + up;
}

// ---------------------------------------------------------------
// final 1x1 conv, 64 outputs per thread (mid re-read 2x instead of 4x)
__global__ void k_final(const float* __restrict__ mid, const float* __restrict__ wt,
                        const float* __restrict__ bias, float* __restrict__ out) {
  int p = (blockIdx.x & 15) * 256 + threadIdx.x;
  int rest = blockIdx.x >> 4;
  int cg = rest & 1;
  int b = rest >> 1;
  if (b >= NB) return;
  const float* mp = mid + (size_t)b * NC * (NH * NW) + p;
  const float* wp = wt + cg * 64 * NC;
  float acc[64];
#pragma unroll
  for (int i = 0; i < 64; i++) acc[i] = bias[cg * 64 + i];
  for (int ci = 0; ci < NC; ci++) {
    float mv = mp[ci * 4096];
#pragma unroll
    for (int i = 0; i < 64; i++) acc[i] = fmaf(wp[i * NC + ci], mv, acc[i]);
  }
#pragma unroll
  for (int i = 0; i < 64; i++) out[((size_t)b * NC + cg * 64 + i) * 4096 + p] = acc[i];
}

// ---------------------------------------------------------------
extern "C" void kernel_launch(void* const* d_in, const int* in_sizes, int n_in,
                              void* d_out, int out_size, void* d_ws, size_t ws_size,
                              hipStream_t stream) {
  const float* x      = (const float*)d_in[0];
  const float* y      = (const float*)d_in[1];
  const float* rel    = (const float*)d_in[2];
  const float* q1_w   = (const float*)d_in[3];
  const float* q1_b   = (const float*)d_in[4];
  const float* q2_w   = (const float*)d_in[5];
  const float* q2_b   = (const float*)d_in[6];
  const float* kv1_w  = (const float*)d_in[7];
  const float* kv1_b  = (const float*)d_in[8];
  const float* kv2_w  = (const float*)d_in[9];
  const float* kv2_b  = (const float*)d_in[10];
  const float* lepe_w = (const float*)d_in[11];
  const float* lepe_b = (const float*)d_in[12];
  const float* out_w  = (const float*)d_in[13];
  const float* out_b  = (const float*)d_in[14];
  const float* temp   = (const float*)d_in[15];
  float* out = (float*)d_out;

  float* ws = (float*)d_ws;
  const size_t SP = (size_t)NB * NC * NTOK;   // 1,048,576
  float* xp     = ws;                  // SP
  float* yp     = xp + SP;             // SP
  float* qbuf   = yp + SP;             // SP
  float* attb   = qbuf + SP;           // SP
  float* mid    = attb + SP;           // 4*SP
  unsigned short* kbf = (unsigned short*)(mid + 4 * SP);  // SP ushorts (2MB)
  unsigned short* vbf = kbf + SP;                         // SP ushorts (2MB)

  k_pool<<<8192, 256, 0, stream>>>(x, y, xp, yp);
  k_qpath<<<256, 1024, 0, stream>>>(xp, q1_w, q1_b, q2_w, q2_b, qbuf);
  k_kvpath<<<512, 1024, 0, stream>>>(yp, kv1_w, kv1_b, kv2_w, kv2_b, kbf, vbf);
  k_attn<<<1024, 512, 0, stream>>>(qbuf, kbf, vbf, rel, temp, attb);
  k_mid<<<16384, 256, 0, stream>>>(x, lepe_w, lepe_b, attb, mid);
  k_final<<<256, 256, 0, stream>>>(mid, out_w, out_b, out);
}

// Round 14
// 245.265 us; speedup vs baseline: 1.2508x; 1.2508x over previous
//
#include <hip/hip_runtime.h>

// Problem constants
#define NB 8
#define NC 128
#define NH 64
#define NW 64
#define HEADS 4
#define HP 32
#define WP 32
#define NTOK 1024     // HP*WP
#define TOPK 32
#define HDIM 32

typedef __fp16 hh2 __attribute__((ext_vector_type(2)));

__device__ __forceinline__ hh2 h2cast(unsigned u) {
  union { unsigned u; hh2 h; } x; x.u = u; return x.h;
}
__device__ __forceinline__ unsigned pkf16(float a, float b) {
  union { hh2 h; unsigned u; } x; x.h = __builtin_amdgcn_cvt_pkrtz(a, b); return x.u;
}

#if __has_builtin(__builtin_amdgcn_fdot2)
__device__ __forceinline__ float fdot2(unsigned kw, unsigned qw, float c) {
  return __builtin_amdgcn_fdot2(h2cast(kw), h2cast(qw), c, false);
}
#else
__device__ __forceinline__ float fdot2(unsigned kw, unsigned qw, float c) {
  hh2 k = h2cast(kw), q = h2cast(qw);
  return fmaf((float)k.x, (float)q.x, fmaf((float)k.y, (float)q.y, c));
}
#endif

// monotone float->uint map (order-preserving) and inverse
__device__ __forceinline__ unsigned fmap(float f) {
  unsigned u = __float_as_uint(f);
  return u ^ ((unsigned)((int)u >> 31) | 0x80000000u);
}
__device__ __forceinline__ float funmap(unsigned k) {
  unsigned uo = k ^ ((unsigned)((int)(~k) >> 31) | 0x80000000u);
  return __uint_as_float(uo);
}

// DPP wave64 max-reduce on unsigned; result broadcast via readlane(63)
__device__ __forceinline__ unsigned wave_maxu(unsigned v) {
#define ST(ctrl)                                                                     \
  {                                                                                  \
    unsigned o = (unsigned)__builtin_amdgcn_update_dpp(0, (int)v, ctrl, 0xF, 0xF, true); \
    v = v > o ? v : o;                                                               \
  }
  ST(0xB1)   // quad_perm [1,0,3,2]
  ST(0x4E)   // quad_perm [2,3,0,1]
  ST(0x141)  // row_half_mirror
  ST(0x140)  // row_mirror
  ST(0x142)  // row_bcast:15
  ST(0x143)  // row_bcast:31
#undef ST
  return (unsigned)__builtin_amdgcn_readlane((int)v, 63);
}

// DPP wave64 float sum-reduce; result broadcast via readlane(63)
__device__ __forceinline__ float wave_sumf(float v) {
#define STA(ctrl)                                                                    \
  v += __int_as_float(__builtin_amdgcn_update_dpp(0, __float_as_int(v), ctrl, 0xF, 0xF, true));
  STA(0xB1)
  STA(0x4E)
  STA(0x141)
  STA(0x140)
  STA(0x142)
  STA(0x143)
#undef STA
  return __int_as_float(__builtin_amdgcn_readlane(__float_as_int(v), 63));
}

// DPP wave64 inclusive prefix-sum on unsigned. Safe for packed 16+16 fields.
__device__ __forceinline__ unsigned wave_iprefix(unsigned v, int lane) {
#define SH(ctrl)                                                                     \
  v += (unsigned)__builtin_amdgcn_update_dpp(0, (int)v, ctrl, 0xF, 0xF, true);
  SH(0x111)  // row_shr:1
  SH(0x112)  // row_shr:2
  SH(0x114)  // row_shr:4
  SH(0x118)  // row_shr:8
#undef SH
  unsigned r0 = (unsigned)__builtin_amdgcn_readlane((int)v, 15);
  unsigned r1 = (unsigned)__builtin_amdgcn_readlane((int)v, 31);
  unsigned r2 = (unsigned)__builtin_amdgcn_readlane((int)v, 47);
  v += (lane >= 16) ? r0 : 0u;
  v += (lane >= 32) ? r1 : 0u;
  v += (lane >= 48) ? r2 : 0u;
  return v;
}

// ---------------------------------------------------------------
// avg pool 2x2 on x and y
__global__ void k_pool(const float* __restrict__ x, const float* __restrict__ y,
                       float* __restrict__ xp, float* __restrict__ yp) {
  int idx = blockIdx.x * 256 + threadIdx.x;
  const int total = NB * NC * HP * WP; // 1,048,576
  if (idx >= 2 * total) return;
  bool isY = idx >= total;
  int i = isY ? idx - total : idx;
  int pw = i & 31, ph = (i >> 5) & 31, bc = i >> 10;
  const float* src = (isY ? y : x) + ((size_t)bc * 64 + ph * 2) * 64 + pw * 2;
  float v = 0.25f * (src[0] + src[1] + src[64] + src[65]);
  (isY ? yp : xp)[i] = v;
}

// ---------------------------------------------------------------
// fused q path: 1x1 conv (4 ch/thread) -> LDS tile -> depthwise 3x3 -> f16
// d-pairs qh[((b*4+h)*1024+n)*16 + d2]. block 1024, grid 8b x 32 quads.
__launch_bounds__(1024, 2)
__global__ void k_qpath(const float* __restrict__ xp, const float* __restrict__ w1,
                        const float* __restrict__ b1, const float* __restrict__ w2,
                        const float* __restrict__ b2, unsigned* __restrict__ qh) {
  __shared__ float cls[4][1024];
  int px = threadIdx.x;
  int q = blockIdx.x & 31;   // channel quad (4 channels)
  int b = blockIdx.x >> 5;
  const float* ip = xp + (size_t)b * NC * NTOK + px;
  const float* wp = w1 + q * 4 * NC;
  float acc[4];
#pragma unroll
  for (int i = 0; i < 4; i++) acc[i] = b1[q * 4 + i];
  for (int ci = 0; ci < NC; ci++) {
    float mv = ip[ci * NTOK];
#pragma unroll
    for (int i = 0; i < 4; i++) acc[i] = fmaf(wp[i * NC + ci], mv, acc[i]);
  }
#pragma unroll
  for (int i = 0; i < 4; i++) cls[i][px] = acc[i];
  __syncthreads();
  int pw = px & 31, ph = px >> 5;
  float aout[4];
#pragma unroll
  for (int i = 0; i < 4; i++) {
    int c = q * 4 + i;
    const float* wq = w2 + c * 9;
    float a = b2[c];
#pragma unroll
    for (int ky = 0; ky < 3; ky++) {
      int ih = ph + ky - 1;
      if (ih < 0 || ih > 31) continue;
#pragma unroll
      for (int kx = 0; kx < 3; kx++) {
        int iw = pw + kx - 1;
        if (iw < 0 || iw > 31) continue;
        a = fmaf(wq[ky * 3 + kx], cls[i][ih * 32 + iw], a);
      }
    }
    aout[i] = a;
  }
  int h = q >> 3;
  int d2 = ((q * 4) & 31) >> 1;
  size_t base = (((size_t)b * HEADS + h) * NTOK + px) * 16;
  qh[base + d2] = pkf16(aout[0], aout[1]);
  qh[base + d2 + 1] = pkf16(aout[2], aout[3]);
}

// ---------------------------------------------------------------
// fused kv path: 1x1 conv (4 ch/thread) -> LDS tile -> grouped 3x3 ->
// K as f16 d-pairs kpair[((b*4+h)*16+d2)*1024+n], V as f16 [b][h][n][d].
// block 1024, grid 8b x 64 quads.
__launch_bounds__(1024, 2)
__global__ void k_kvpath(const float* __restrict__ yp, const float* __restrict__ w1,
                         const float* __restrict__ b1, const float* __restrict__ w2,
                         const float* __restrict__ b2, unsigned* __restrict__ kpair,
                         unsigned short* __restrict__ vbf) {
  __shared__ float cls[4][1024];
  int px = threadIdx.x;
  int q = blockIdx.x & 63;   // channel quad of the 256 kv1 channels
  int b = blockIdx.x >> 6;
  const float* ip = yp + (size_t)b * NC * NTOK + px;
  const float* wp = w1 + q * 4 * NC;
  float acc[4];
#pragma unroll
  for (int i = 0; i < 4; i++) acc[i] = b1[q * 4 + i];
  for (int ci = 0; ci < NC; ci++) {
    float mv = ip[ci * NTOK];
#pragma unroll
    for (int i = 0; i < 4; i++) acc[i] = fmaf(wp[i * NC + ci], mv, acc[i]);
  }
#pragma unroll
  for (int i = 0; i < 4; i++) cls[i][px] = acc[i];
  __syncthreads();
  int pw = px & 31, ph = px >> 5;
  float aout[4];
#pragma unroll
  for (int i = 0; i < 4; i++) {
    int o = q * 4 + i;       // kv channel 0..255
    int l0 = i & ~1;         // group's first input channel within the quad
    const float* wq = w2 + o * 18; // [2][3][3]
    float a = b2[o];
#pragma unroll
    for (int ky = 0; ky < 3; ky++) {
      int ih = ph + ky - 1;
      if (ih < 0 || ih > 31) continue;
#pragma unroll
      for (int kx = 0; kx < 3; kx++) {
        int iw = pw + kx - 1;
        if (iw < 0 || iw > 31) continue;
        a = fmaf(wq[ky * 3 + kx], cls[l0][ih * 32 + iw], a);
        a = fmaf(wq[9 + ky * 3 + kx], cls[l0 + 1][ih * 32 + iw], a);
      }
    }
    aout[i] = a;
  }
  if (q < 32) {
    // K channels: quad = 4 consecutive d within head h
    int h = q >> 3;
    int d2 = ((q * 4) & 31) >> 1;
    size_t base = (((size_t)b * HEADS + h) * 16) * NTOK + px;
    kpair[base + (size_t)d2 * NTOK] = pkf16(aout[0], aout[1]);
    kpair[base + (size_t)(d2 + 1) * NTOK] = pkf16(aout[2], aout[3]);
  } else {
    // V channels
#pragma unroll
    for (int i = 0; i < 4; i++) {
      int c = q * 4 + i - 128;
      int h = c >> 5, d = c & 31;
      union { __fp16 h; unsigned short u; } cv;
      cv.h = (__fp16)aout[i];
      vbf[(((size_t)b * HEADS + h) * NTOK + px) * HDIM + d] = cv.u;
    }
  }
}

// ---------------------------------------------------------------
// attention v10: v8 structure (2 rows/wave) + f16 dot2 QK (no unpack).
// grid: 2048 = 64 chunks x 4 h x 8 b; block 512 (8 waves), 2 rows per wave.
__launch_bounds__(512, 2)
__global__ void k_attn(const unsigned* __restrict__ qh, const unsigned* __restrict__ kpair,
                       const unsigned short* __restrict__ vbf, const float* __restrict__ rel,
                       const float* __restrict__ temp, float* __restrict__ att) {
  __shared__ __align__(16) unsigned ksh[16384];  // f16 K pairs [d2][n], 64KB
  __shared__ __align__(16) unsigned cbuf[8 * 64]; // per-wave 32x(key,token), 2KB

  int bid = blockIdx.x;
  int chunk = bid & 63;
  int h = (bid >> 6) & 3;
  int b = bid >> 8;
  int tid = threadIdx.x;
  int lane = tid & 63;
  int wave = __builtin_amdgcn_readfirstlane(tid >> 6); // 0..7, uniform

  // stage K pairs: 16384 u32 = 8192 uint2, 512 threads x 16
  const uint2* kg = (const uint2*)(kpair + ((size_t)b * HEADS + h) * 16 * NTOK);
  uint2* kl = (uint2*)ksh;
#pragma unroll
  for (int i = 0; i < 16; i++) kl[tid + i * 512] = kg[tid + i * 512];
  __syncthreads();

  const float tmpr = temp[h];
  const unsigned short* vb = vbf + ((size_t)(b * HEADS + h)) * NTOK * HDIM;
  int vlane = lane & 31;
  unsigned* row_lds = cbuf + wave * 64; // 32 entries x 8B, private per wave

  int qbase = chunk * 16 + wave * 2;

  // load q pairs for both rows (wave-uniform broadcast loads)
  unsigned qp[2][16];
#pragma unroll
  for (int r = 0; r < 2; r++) {
    const uint4* q4 = (const uint4*)(qh + (((size_t)b * HEADS + h) * NTOK + qbase + r) * 16);
#pragma unroll
    for (int i = 0; i < 4; i++) {
      uint4 t = q4[i];
      qp[r][i * 4 + 0] = t.x;
      qp[r][i * 4 + 1] = t.y;
      qp[r][i * 4 + 2] = t.z;
      qp[r][i * 4 + 3] = t.w;
    }
  }

  // logits via f16 dot2: acc[r][e] += K[d2](tok) . q[r][d2]
  float acc[2][16];
#pragma unroll
  for (int r = 0; r < 2; r++)
#pragma unroll
    for (int e = 0; e < 16; e++) acc[r][e] = 0.f;

#pragma unroll 4
  for (int d2 = 0; d2 < 16; d2++) {
#pragma unroll
    for (int i = 0; i < 4; i++) {
      uint4 kw = *(const uint4*)&ksh[d2 * 1024 + i * 256 + lane * 4]; // tokens i*256+lane*4+m
      acc[0][i * 4 + 0] = fdot2(kw.x, qp[0][d2], acc[0][i * 4 + 0]);
      acc[0][i * 4 + 1] = fdot2(kw.y, qp[0][d2], acc[0][i * 4 + 1]);
      acc[0][i * 4 + 2] = fdot2(kw.z, qp[0][d2], acc[0][i * 4 + 2]);
      acc[0][i * 4 + 3] = fdot2(kw.w, qp[0][d2], acc[0][i * 4 + 3]);
      acc[1][i * 4 + 0] = fdot2(kw.x, qp[1][d2], acc[1][i * 4 + 0]);
      acc[1][i * 4 + 1] = fdot2(kw.y, qp[1][d2], acc[1][i * 4 + 1]);
      acc[1][i * 4 + 2] = fdot2(kw.z, qp[1][d2], acc[1][i * 4 + 2]);
      acc[1][i * 4 + 3] = fdot2(kw.w, qp[1][d2], acc[1][i * 4 + 3]);
    }
  }

  // pack keys, fusing rel
  const float4* relp = (const float4*)(rel + (((size_t)b * HEADS + h) * NTOK + qbase) * NTOK);
  unsigned kk[2][16];
#pragma unroll
  for (int r = 0; r < 2; r++) {
#pragma unroll
    for (int i = 0; i < 4; i++) {
      float4 rv = relp[r * 256 + i * 64 + lane];
      kk[r][i * 4 + 0] = fmap(fmaf(tmpr, acc[r][i * 4 + 0], rv.x));
      kk[r][i * 4 + 1] = fmap(fmaf(tmpr, acc[r][i * 4 + 1], rv.y));
      kk[r][i * 4 + 2] = fmap(fmaf(tmpr, acc[r][i * 4 + 2], rv.z));
      kk[r][i * 4 + 3] = fmap(fmaf(tmpr, acc[r][i * 4 + 3], rv.w));
    }
  }

  // wave max per row (bsearch upper bound + softmax max)
  unsigned M[2];
#pragma unroll
  for (int r = 0; r < 2; r++) {
    unsigned mx = kk[r][0];
#pragma unroll
    for (int e = 1; e < 16; e++) mx = mx > kk[r][e] ? mx : kk[r][e];
    M[r] = wave_maxu(mx);
  }

  // early-exit binary search; cap 32 -> exact-tie fallback
  unsigned lo0 = 0u, hi0 = M[0], lo1 = 0u, hi1 = M[1];
  unsigned T0x = 0u, T1x = 0u;
  bool d0 = false, d1 = false;
#pragma unroll 1
  for (int it = 0; it < 32; it++) {
    if (d0 && d1) break;
    if (!d0) {
      unsigned mid = lo0 + ((hi0 - lo0) >> 1);
      int c = 0;
#pragma unroll
      for (int e = 0; e < 16; e++) c += (int)__popcll(__ballot(kk[0][e] > mid));
      if (c >= TOPK) lo0 = mid; else hi0 = mid;
      if (c == TOPK) { T0x = mid; d0 = true; }
    }
    if (!d1) {
      unsigned mid = lo1 + ((hi1 - lo1) >> 1);
      int c = 0;
#pragma unroll
      for (int e = 0; e < 16; e++) c += (int)__popcll(__ballot(kk[1][e] > mid));
      if (c >= TOPK) lo1 = mid; else hi1 = mid;
      if (c == TOPK) { T1x = mid; d1 = true; }
    }
  }
  unsigned T[2];
  T[0] = d0 ? T0x : hi0;
  T[1] = d1 ? T1x : hi1;

  // per-row: tie handling, compaction, softmax + V gather
#pragma unroll
  for (int r = 0; r < 2; r++) {
    unsigned gtc = 0, tq = 0;
#pragma unroll
    for (int e = 0; e < 16; e++) {
      gtc += (kk[r][e] > T[r]) ? 1u : 0u;
      tq += (kk[r][e] == T[r]) ? 1u : 0u;
    }
    unsigned packed = gtc | (tq << 16);
    unsigned incl = wave_iprefix(packed, lane);
    unsigned tot = (unsigned)__builtin_amdgcn_readlane((int)incl, 63);
    unsigned n_gt = tot & 0xFFFFu;
    unsigned tie_pfx = (incl >> 16) - tq;
    unsigned extras = (unsigned)TOPK - n_gt; // 0 on early-exit rows
    int el = (int)extras - (int)tie_pfx;
    el = el < 0 ? 0 : el;
    el = el > (int)tq ? (int)tq : el;
    unsigned sc = gtc + (unsigned)el;
    unsigned wbase = wave_iprefix(sc, lane) - sc;

    unsigned wp = wbase, tr = tie_pfx;
#pragma unroll
    for (int e = 0; e < 16; e++) {
      bool gt = kk[r][e] > T[r];
      bool eq = (kk[r][e] == T[r]);
      bool take = gt || (eq && (tr < extras));
      tr += eq ? 1u : 0u;
      if (take) {
        ((uint2*)row_lds)[wp] = make_uint2(kk[r][e], (unsigned)((e >> 2) * 256 + lane * 4 + (e & 3)));
        wp++;
      }
    }

    // parallel softmax over the 32 entries (lanes 0..31) + pipelined V gather
    uint2 ent = ((const uint2*)row_lds)[vlane];
    float fv = funmap(ent.x);
    float mv = funmap(M[r]);
    float e_ = __expf(fv - mv);
    e_ = (lane < TOPK) ? e_ : 0.f;
    float se = wave_sumf(e_);

    float oacc = 0.f;
#pragma unroll
    for (int t = 0; t < TOPK; t++) {
      float es = __int_as_float(__builtin_amdgcn_readlane(__float_as_int(e_), t));
      int tok = __builtin_amdgcn_readlane((int)ent.y, t);
      union { unsigned short u; __fp16 h; } cv;
      cv.u = vb[(size_t)tok * HDIM + vlane];
      oacc = fmaf(es, (float)cv.h, oacc);
    }

    if (lane < HDIM) {
      att[((size_t)b * NC + h * HDIM + lane) * NTOK + (qbase + r)] = oacc / se;
    }
  }
}

// ---------------------------------------------------------------
// bilinear 2x upsample weights (jax scale_and_translate semantics)
__device__ __forceinline__ void bil(int i, int& j0, int& j1, float& wa, float& wb) {
  if (i & 1) {
    j0 = i >> 1; j1 = j0 + 1; wa = 0.75f; wb = 0.25f;
    if (j1 > 31) { j1 = 31; wa = 1.f; wb = 0.f; }
  } else {
    j0 = (i >> 1) - 1; j1 = j0 + 1; wa = 0.25f; wb = 0.75f;
    if (j0 < 0) { j0 = 0; wa = 0.f; wb = 1.f; }
  }
}

// mid = lepe(x) + upsample(att) ; (B,128,64,64)
__global__ void k_mid(const float* __restrict__ x, const float* __restrict__ lepe_w,
                      const float* __restrict__ lepe_b, const float* __restrict__ att,
                      float* __restrict__ mid) {
  int t = blockIdx.x * 256 + threadIdx.x;
  if (t >= NB * NC * NH * NW) return;
  int w = t & 63;
  int h0 = (t >> 6) & 63;
  int bc = t >> 12;
  int c = bc & 127;
  const float* xp = x + (size_t)bc * (NH * NW);
  const float* wp = lepe_w + c * 25;
  float acc = lepe_b[c];
#pragma unroll
  for (int ky = 0; ky < 5; ky++) {
    int ih = h0 + ky - 2;
    if (ih < 0 || ih > 63) continue;
#pragma unroll
    for (int kx = 0; kx < 5; kx++) {
      int iw = w + kx - 2;
      if (iw < 0 || iw > 63) continue;
      acc = fmaf(wp[ky * 5 + kx], xp[ih * 64 + iw], acc);
    }
  }
  int jh0, jh1, jw0, jw1;
  float wha, whb, wwa, wwb;
  bil(h0, jh0, jh1, wha, whb);
  bil(w, jw0, jw1, wwa, wwb);
  const float* ap = att + (size_t)bc * NTOK;
  float up = wha * (wwa * ap[jh0 * 32 + jw0] + wwb * ap[jh0 * 32 + jw1]) +
             whb * (wwa * ap[jh1 * 32 + jw0] + wwb * ap[jh1 * 32 + jw1]);
  mid[t] = acc + up;
}

// ---------------------------------------------------------------
// final 1x1 conv, 64 outputs per thread (mid re-read 2x)
__global__ void k_final(const float* __restrict__ mid, const float* __restrict__ wt,
                        const float* __restrict__ bias, float* __restrict__ out) {
  int p = (blockIdx.x & 15) * 256 + threadIdx.x;
  int rest = blockIdx.x >> 4;
  int cg = rest & 1;
  int b = rest >> 1;
  if (b >= NB) return;
  const float* mp = mid + (size_t)b * NC * (NH * NW) + p;
  const float* wp = wt + cg * 64 * NC;
  float acc[64];
#pragma unroll
  for (int i = 0; i < 64; i++) acc[i] = bias[cg * 64 + i];
  for (int ci = 0; ci < NC; ci++) {
    float mv = mp[ci * 4096];
#pragma unroll
    for (int i = 0; i < 64; i++) acc[i] = fmaf(wp[i * NC + ci], mv, acc[i]);
  }
#pragma unroll
  for (int i = 0; i < 64; i++) out[((size_t)b * NC + cg * 64 + i) * 4096 + p] = acc[i];
}

// ---------------------------------------------------------------
extern "C" void kernel_launch(void* const* d_in, const int* in_sizes, int n_in,
                              void* d_out, int out_size, void* d_ws, size_t ws_size,
                              hipStream_t stream) {
  const float* x      = (const float*)d_in[0];
  const float* y      = (const float*)d_in[1];
  const float* rel    = (const float*)d_in[2];
  const float* q1_w   = (const float*)d_in[3];
  const float* q1_b   = (const float*)d_in[4];
  const float* q2_w   = (const float*)d_in[5];
  const float* q2_b   = (const float*)d_in[6];
  const float* kv1_w  = (const float*)d_in[7];
  const float* kv1_b  = (const float*)d_in[8];
  const float* kv2_w  = (const float*)d_in[9];
  const float* kv2_b  = (const float*)d_in[10];
  const float* lepe_w = (const float*)d_in[11];
  const float* lepe_b = (const float*)d_in[12];
  const float* out_w  = (const float*)d_in[13];
  const float* out_b  = (const float*)d_in[14];
  const float* temp   = (const float*)d_in[15];
  float* out = (float*)d_out;

  float* ws = (float*)d_ws;
  const size_t SP = (size_t)NB * NC * NTOK;   // 1,048,576
  float* xp     = ws;                  // SP
  float* yp     = xp + SP;             // SP
  float* attb   = yp + SP;             // SP
  float* mid    = attb + SP;           // 4*SP
  unsigned* qh    = (unsigned*)(mid + 4 * SP);    // 524288 u32 (2MB)
  unsigned* kpair = qh + 524288;                  // 524288 u32 (2MB)
  unsigned short* vbf = (unsigned short*)(kpair + 524288); // SP ushorts (2MB)

  k_pool<<<8192, 256, 0, stream>>>(x, y, xp, yp);
  k_qpath<<<256, 1024, 0, stream>>>(xp, q1_w, q1_b, q2_w, q2_b, qh);
  k_kvpath<<<512, 1024, 0, stream>>>(yp, kv1_w, kv1_b, kv2_w, kv2_b, kpair, vbf);
  k_attn<<<2048, 512, 0, stream>>>(qh, kpair, vbf, rel, temp, attb);
  k_mid<<<16384, 256, 0, stream>>>(x, lepe_w, lepe_b, attb, mid);
  k_final<<<256, 256, 0, stream>>>(mid, out_w, out_b, out);
}

// Round 15
// 222.094 us; speedup vs baseline: 1.3813x; 1.1043x over previous
//
#include <hip/hip_runtime.h>

// Problem constants
#define NB 8
#define NC 128
#define NH 64
#define NW 64
#define HEADS 4
#define HP 32
#define WP 32
#define NTOK 1024     // HP*WP
#define TOPK 32
#define HDIM 32

typedef __fp16 hh2 __attribute__((ext_vector_type(2)));

__device__ __forceinline__ hh2 h2cast(unsigned u) {
  union { unsigned u; hh2 h; } x; x.u = u; return x.h;
}
__device__ __forceinline__ unsigned pkf16(float a, float b) {
  union { hh2 h; unsigned u; } x; x.h = __builtin_amdgcn_cvt_pkrtz(a, b); return x.u;
}

#if __has_builtin(__builtin_amdgcn_fdot2)
__device__ __forceinline__ float fdot2(unsigned kw, unsigned qw, float c) {
  return __builtin_amdgcn_fdot2(h2cast(kw), h2cast(qw), c, false);
}
#else
__device__ __forceinline__ float fdot2(unsigned kw, unsigned qw, float c) {
  hh2 k = h2cast(kw), q = h2cast(qw);
  return fmaf((float)k.x, (float)q.x, fmaf((float)k.y, (float)q.y, c));
}
#endif

// monotone float->uint map (order-preserving) and inverse
__device__ __forceinline__ unsigned fmap(float f) {
  unsigned u = __float_as_uint(f);
  return u ^ ((unsigned)((int)u >> 31) | 0x80000000u);
}
__device__ __forceinline__ float funmap(unsigned k) {
  unsigned uo = k ^ ((unsigned)((int)(~k) >> 31) | 0x80000000u);
  return __uint_as_float(uo);
}

// DPP wave64 max-reduce on unsigned; result broadcast via readlane(63)
__device__ __forceinline__ unsigned wave_maxu(unsigned v) {
#define ST(ctrl)                                                                     \
  {                                                                                  \
    unsigned o = (unsigned)__builtin_amdgcn_update_dpp(0, (int)v, ctrl, 0xF, 0xF, true); \
    v = v > o ? v : o;                                                               \
  }
  ST(0xB1)   // quad_perm [1,0,3,2]
  ST(0x4E)   // quad_perm [2,3,0,1]
  ST(0x141)  // row_half_mirror
  ST(0x140)  // row_mirror
  ST(0x142)  // row_bcast:15
  ST(0x143)  // row_bcast:31
#undef ST
  return (unsigned)__builtin_amdgcn_readlane((int)v, 63);
}

// DPP wave64 float sum-reduce; result broadcast via readlane(63)
__device__ __forceinline__ float wave_sumf(float v) {
#define STA(ctrl)                                                                    \
  v += __int_as_float(__builtin_amdgcn_update_dpp(0, __float_as_int(v), ctrl, 0xF, 0xF, true));
  STA(0xB1)
  STA(0x4E)
  STA(0x141)
  STA(0x140)
  STA(0x142)
  STA(0x143)
#undef STA
  return __int_as_float(__builtin_amdgcn_readlane(__float_as_int(v), 63));
}

// DPP wave64 inclusive prefix-sum on unsigned. Safe for packed 16+16 fields.
__device__ __forceinline__ unsigned wave_iprefix(unsigned v, int lane) {
#define SH(ctrl)                                                                     \
  v += (unsigned)__builtin_amdgcn_update_dpp(0, (int)v, ctrl, 0xF, 0xF, true);
  SH(0x111)  // row_shr:1
  SH(0x112)  // row_shr:2
  SH(0x114)  // row_shr:4
  SH(0x118)  // row_shr:8
#undef SH
  unsigned r0 = (unsigned)__builtin_amdgcn_readlane((int)v, 15);
  unsigned r1 = (unsigned)__builtin_amdgcn_readlane((int)v, 31);
  unsigned r2 = (unsigned)__builtin_amdgcn_readlane((int)v, 47);
  v += (lane >= 16) ? r0 : 0u;
  v += (lane >= 32) ? r1 : 0u;
  v += (lane >= 48) ? r2 : 0u;
  return v;
}

// ---------------------------------------------------------------
// pack conv weights to f16 ci-pairs: [0..8191]=q1, [8192..24575]=kv1,
// [24576..32767]=out. row layout: wph[base + co*64 + ci2]
__global__ void k_pack(const float* __restrict__ q1w, const float* __restrict__ kv1w,
                       const float* __restrict__ outw, unsigned* __restrict__ wph) {
  int i = blockIdx.x * 256 + threadIdx.x;
  if (i >= 32768) return;
  const float* src;
  int off;
  if (i < 8192) { src = q1w; off = i; }
  else if (i < 24576) { src = kv1w; off = i - 8192; }
  else { src = outw; off = i - 24576; }
  int co = off >> 6, ci2 = off & 63;
  wph[i] = pkf16(src[co * 128 + 2 * ci2], src[co * 128 + 2 * ci2 + 1]);
}

// ---------------------------------------------------------------
// avg pool 2x2 on x and y -> f16 channel-pairs xph/yph[(b*64+c2)*1024+p]
__global__ void k_pool(const float* __restrict__ x, const float* __restrict__ y,
                       unsigned* __restrict__ xph, unsigned* __restrict__ yph) {
  int idx = blockIdx.x * 256 + threadIdx.x;
  const int total = NB * 64 * NTOK; // 524288 pairs per array
  if (idx >= 2 * total) return;
  bool isY = idx >= total;
  int i = isY ? idx - total : idx;
  int p = i & 1023;
  int pw = p & 31, ph = p >> 5;
  int bc2 = i >> 10;
  int c2 = bc2 & 63, b = bc2 >> 6;
  const float* s0 = (isY ? y : x) + (((size_t)b * NC + 2 * c2) * 64 + ph * 2) * 64 + pw * 2;
  const float* s1 = s0 + 4096;
  float v0 = 0.25f * (s0[0] + s0[1] + s0[64] + s0[65]);
  float v1 = 0.25f * (s1[0] + s1[1] + s1[64] + s1[65]);
  (isY ? yph : xph)[i] = pkf16(v0, v1);
}

// ---------------------------------------------------------------
// fused q path: f16-dot2 1x1 conv (4 ch/thread) -> LDS tile -> depthwise 3x3
// -> f16 d-pairs qh[((b*4+h)*1024+n)*16 + d2]. block 1024, grid 8b x 32 quads.
__launch_bounds__(1024, 2)
__global__ void k_qpath(const unsigned* __restrict__ xph, const unsigned* __restrict__ wph,
                        const float* __restrict__ b1, const float* __restrict__ w2,
                        const float* __restrict__ b2, unsigned* __restrict__ qh) {
  __shared__ float cls[4][1024];
  int px = threadIdx.x;
  int q = blockIdx.x & 31;   // channel quad (4 channels)
  int b = blockIdx.x >> 5;
  const unsigned* ip = xph + (size_t)b * 64 * NTOK + px;
  const unsigned* wp = wph + q * 4 * 64; // q1h base
  float acc[4];
#pragma unroll
  for (int i = 0; i < 4; i++) acc[i] = b1[q * 4 + i];
  for (int ci2 = 0; ci2 < 64; ci2++) {
    unsigned mv = ip[ci2 * NTOK];
#pragma unroll
    for (int i = 0; i < 4; i++) acc[i] = fdot2(mv, wp[i * 64 + ci2], acc[i]);
  }
#pragma unroll
  for (int i = 0; i < 4; i++) cls[i][px] = acc[i];
  __syncthreads();
  int pw = px & 31, ph = px >> 5;
  float aout[4];
#pragma unroll
  for (int i = 0; i < 4; i++) {
    int c = q * 4 + i;
    const float* wq = w2 + c * 9;
    float a = b2[c];
#pragma unroll
    for (int ky = 0; ky < 3; ky++) {
      int ih = ph + ky - 1;
      if (ih < 0 || ih > 31) continue;
#pragma unroll
      for (int kx = 0; kx < 3; kx++) {
        int iw = pw + kx - 1;
        if (iw < 0 || iw > 31) continue;
        a = fmaf(wq[ky * 3 + kx], cls[i][ih * 32 + iw], a);
      }
    }
    aout[i] = a;
  }
  int h = q >> 3;
  int d2 = ((q * 4) & 31) >> 1;
  size_t base = (((size_t)b * HEADS + h) * NTOK + px) * 16;
  qh[base + d2] = pkf16(aout[0], aout[1]);
  qh[base + d2 + 1] = pkf16(aout[2], aout[3]);
}

// ---------------------------------------------------------------
// fused kv path: f16-dot2 1x1 conv -> LDS tile -> grouped 3x3 ->
// K as f16 d-pairs kpair[((b*4+h)*16+d2)*1024+n], V as f16 [b][h][n][d].
__launch_bounds__(1024, 2)
__global__ void k_kvpath(const unsigned* __restrict__ yph, const unsigned* __restrict__ wph,
                         const float* __restrict__ b1, const float* __restrict__ w2,
                         const float* __restrict__ b2, unsigned* __restrict__ kpair,
                         unsigned short* __restrict__ vbf) {
  __shared__ float cls[4][1024];
  int px = threadIdx.x;
  int q = blockIdx.x & 63;   // channel quad of the 256 kv1 channels
  int b = blockIdx.x >> 6;
  const unsigned* ip = yph + (size_t)b * 64 * NTOK + px;
  const unsigned* wp = wph + 8192 + q * 4 * 64; // kv1h base
  float acc[4];
#pragma unroll
  for (int i = 0; i < 4; i++) acc[i] = b1[q * 4 + i];
  for (int ci2 = 0; ci2 < 64; ci2++) {
    unsigned mv = ip[ci2 * NTOK];
#pragma unroll
    for (int i = 0; i < 4; i++) acc[i] = fdot2(mv, wp[i * 64 + ci2], acc[i]);
  }
#pragma unroll
  for (int i = 0; i < 4; i++) cls[i][px] = acc[i];
  __syncthreads();
  int pw = px & 31, ph = px >> 5;
  float aout[4];
#pragma unroll
  for (int i = 0; i < 4; i++) {
    int o = q * 4 + i;       // kv channel 0..255
    int l0 = i & ~1;         // group's first input channel within the quad
    const float* wq = w2 + o * 18; // [2][3][3]
    float a = b2[o];
#pragma unroll
    for (int ky = 0; ky < 3; ky++) {
      int ih = ph + ky - 1;
      if (ih < 0 || ih > 31) continue;
#pragma unroll
      for (int kx = 0; kx < 3; kx++) {
        int iw = pw + kx - 1;
        if (iw < 0 || iw > 31) continue;
        a = fmaf(wq[ky * 3 + kx], cls[l0][ih * 32 + iw], a);
        a = fmaf(wq[9 + ky * 3 + kx], cls[l0 + 1][ih * 32 + iw], a);
      }
    }
    aout[i] = a;
  }
  if (q < 32) {
    // K channels: quad = 4 consecutive d within head h
    int h = q >> 3;
    int d2 = ((q * 4) & 31) >> 1;
    size_t base = (((size_t)b * HEADS + h) * 16) * NTOK + px;
    kpair[base + (size_t)d2 * NTOK] = pkf16(aout[0], aout[1]);
    kpair[base + (size_t)(d2 + 1) * NTOK] = pkf16(aout[2], aout[3]);
  } else {
    // V channels
#pragma unroll
    for (int i = 0; i < 4; i++) {
      int c = q * 4 + i - 128;
      int h = c >> 5, d = c & 31;
      union { __fp16 h; unsigned short u; } cv;
      cv.h = (__fp16)aout[i];
      vbf[(((size_t)b * HEADS + h) * NTOK + px) * HDIM + d] = cv.u;
    }
  }
}

// ---------------------------------------------------------------
// attention v10 (unchanged from round 14): 2 rows/wave, f16 dot2 QK,
// early-exit bsearch top-32, compaction, parallel softmax + V gather.
__launch_bounds__(512, 2)
__global__ void k_attn(const unsigned* __restrict__ qh, const unsigned* __restrict__ kpair,
                       const unsigned short* __restrict__ vbf, const float* __restrict__ rel,
                       const float* __restrict__ temp, float* __restrict__ att) {
  __shared__ __align__(16) unsigned ksh[16384];  // f16 K pairs [d2][n], 64KB
  __shared__ __align__(16) unsigned cbuf[8 * 64]; // per-wave 32x(key,token), 2KB

  int bid = blockIdx.x;
  int chunk = bid & 63;
  int h = (bid >> 6) & 3;
  int b = bid >> 8;
  int tid = threadIdx.x;
  int lane = tid & 63;
  int wave = __builtin_amdgcn_readfirstlane(tid >> 6); // 0..7, uniform

  // stage K pairs: 16384 u32 = 8192 uint2, 512 threads x 16
  const uint2* kg = (const uint2*)(kpair + ((size_t)b * HEADS + h) * 16 * NTOK);
  uint2* kl = (uint2*)ksh;
#pragma unroll
  for (int i = 0; i < 16; i++) kl[tid + i * 512] = kg[tid + i * 512];
  __syncthreads();

  const float tmpr = temp[h];
  const unsigned short* vb = vbf + ((size_t)(b * HEADS + h)) * NTOK * HDIM;
  int vlane = lane & 31;
  unsigned* row_lds = cbuf + wave * 64; // 32 entries x 8B, private per wave

  int qbase = chunk * 16 + wave * 2;

  // load q pairs for both rows (wave-uniform broadcast loads)
  unsigned qp[2][16];
#pragma unroll
  for (int r = 0; r < 2; r++) {
    const uint4* q4 = (const uint4*)(qh + (((size_t)b * HEADS + h) * NTOK + qbase + r) * 16);
#pragma unroll
    for (int i = 0; i < 4; i++) {
      uint4 t = q4[i];
      qp[r][i * 4 + 0] = t.x;
      qp[r][i * 4 + 1] = t.y;
      qp[r][i * 4 + 2] = t.z;
      qp[r][i * 4 + 3] = t.w;
    }
  }

  // logits via f16 dot2: acc[r][e] += K[d2](tok) . q[r][d2]
  float acc[2][16];
#pragma unroll
  for (int r = 0; r < 2; r++)
#pragma unroll
    for (int e = 0; e < 16; e++) acc[r][e] = 0.f;

#pragma unroll 4
  for (int d2 = 0; d2 < 16; d2++) {
#pragma unroll
    for (int i = 0; i < 4; i++) {
      uint4 kw = *(const uint4*)&ksh[d2 * 1024 + i * 256 + lane * 4]; // tokens i*256+lane*4+m
      acc[0][i * 4 + 0] = fdot2(kw.x, qp[0][d2], acc[0][i * 4 + 0]);
      acc[0][i * 4 + 1] = fdot2(kw.y, qp[0][d2], acc[0][i * 4 + 1]);
      acc[0][i * 4 + 2] = fdot2(kw.z, qp[0][d2], acc[0][i * 4 + 2]);
      acc[0][i * 4 + 3] = fdot2(kw.w, qp[0][d2], acc[0][i * 4 + 3]);
      acc[1][i * 4 + 0] = fdot2(kw.x, qp[1][d2], acc[1][i * 4 + 0]);
      acc[1][i * 4 + 1] = fdot2(kw.y, qp[1][d2], acc[1][i * 4 + 1]);
      acc[1][i * 4 + 2] = fdot2(kw.z, qp[1][d2], acc[1][i * 4 + 2]);
      acc[1][i * 4 + 3] = fdot2(kw.w, qp[1][d2], acc[1][i * 4 + 3]);
    }
  }

  // pack keys, fusing rel
  const float4* relp = (const float4*)(rel + (((size_t)b * HEADS + h) * NTOK + qbase) * NTOK);
  unsigned kk[2][16];
#pragma unroll
  for (int r = 0; r < 2; r++) {
#pragma unroll
    for (int i = 0; i < 4; i++) {
      float4 rv = relp[r * 256 + i * 64 + lane];
      kk[r][i * 4 + 0] = fmap(fmaf(tmpr, acc[r][i * 4 + 0], rv.x));
      kk[r][i * 4 + 1] = fmap(fmaf(tmpr, acc[r][i * 4 + 1], rv.y));
      kk[r][i * 4 + 2] = fmap(fmaf(tmpr, acc[r][i * 4 + 2], rv.z));
      kk[r][i * 4 + 3] = fmap(fmaf(tmpr, acc[r][i * 4 + 3], rv.w));
    }
  }

  // wave max per row (bsearch upper bound + softmax max)
  unsigned M[2];
#pragma unroll
  for (int r = 0; r < 2; r++) {
    unsigned mx = kk[r][0];
#pragma unroll
    for (int e = 1; e < 16; e++) mx = mx > kk[r][e] ? mx : kk[r][e];
    M[r] = wave_maxu(mx);
  }

  // early-exit binary search; cap 32 -> exact-tie fallback
  unsigned lo0 = 0u, hi0 = M[0], lo1 = 0u, hi1 = M[1];
  unsigned T0x = 0u, T1x = 0u;
  bool d0 = false, d1 = false;
#pragma unroll 1
  for (int it = 0; it < 32; it++) {
    if (d0 && d1) break;
    if (!d0) {
      unsigned mid = lo0 + ((hi0 - lo0) >> 1);
      int c = 0;
#pragma unroll
      for (int e = 0; e < 16; e++) c += (int)__popcll(__ballot(kk[0][e] > mid));
      if (c >= TOPK) lo0 = mid; else hi0 = mid;
      if (c == TOPK) { T0x = mid; d0 = true; }
    }
    if (!d1) {
      unsigned mid = lo1 + ((hi1 - lo1) >> 1);
      int c = 0;
#pragma unroll
      for (int e = 0; e < 16; e++) c += (int)__popcll(__ballot(kk[1][e] > mid));
      if (c >= TOPK) lo1 = mid; else hi1 = mid;
      if (c == TOPK) { T1x = mid; d1 = true; }
    }
  }
  unsigned T[2];
  T[0] = d0 ? T0x : hi0;
  T[1] = d1 ? T1x : hi1;

  // per-row: tie handling, compaction, softmax + V gather
#pragma unroll
  for (int r = 0; r < 2; r++) {
    unsigned gtc = 0, tq = 0;
#pragma unroll
    for (int e = 0; e < 16; e++) {
      gtc += (kk[r][e] > T[r]) ? 1u : 0u;
      tq += (kk[r][e] == T[r]) ? 1u : 0u;
    }
    unsigned packed = gtc | (tq << 16);
    unsigned incl = wave_iprefix(packed, lane);
    unsigned tot = (unsigned)__builtin_amdgcn_readlane((int)incl, 63);
    unsigned n_gt = tot & 0xFFFFu;
    unsigned tie_pfx = (incl >> 16) - tq;
    unsigned extras = (unsigned)TOPK - n_gt; // 0 on early-exit rows
    int el = (int)extras - (int)tie_pfx;
    el = el < 0 ? 0 : el;
    el = el > (int)tq ? (int)tq : el;
    unsigned sc = gtc + (unsigned)el;
    unsigned wbase = wave_iprefix(sc, lane) - sc;

    unsigned wp = wbase, tr = tie_pfx;
#pragma unroll
    for (int e = 0; e < 16; e++) {
      bool gt = kk[r][e] > T[r];
      bool eq = (kk[r][e] == T[r]);
      bool take = gt || (eq && (tr < extras));
      tr += eq ? 1u : 0u;
      if (take) {
        ((uint2*)row_lds)[wp] = make_uint2(kk[r][e], (unsigned)((e >> 2) * 256 + lane * 4 + (e & 3)));
        wp++;
      }
    }

    // parallel softmax over the 32 entries (lanes 0..31) + pipelined V gather
    uint2 ent = ((const uint2*)row_lds)[vlane];
    float fv = funmap(ent.x);
    float mv = funmap(M[r]);
    float e_ = __expf(fv - mv);
    e_ = (lane < TOPK) ? e_ : 0.f;
    float se = wave_sumf(e_);

    float oacc = 0.f;
#pragma unroll
    for (int t = 0; t < TOPK; t++) {
      float es = __int_as_float(__builtin_amdgcn_readlane(__float_as_int(e_), t));
      int tok = __builtin_amdgcn_readlane((int)ent.y, t);
      union { unsigned short u; __fp16 h; } cv;
      cv.u = vb[(size_t)tok * HDIM + vlane];
      oacc = fmaf(es, (float)cv.h, oacc);
    }

    if (lane < HDIM) {
      att[((size_t)b * NC + h * HDIM + lane) * NTOK + (qbase + r)] = oacc / se;
    }
  }
}

// ---------------------------------------------------------------
// bilinear 2x upsample weights (jax scale_and_translate semantics)
__device__ __forceinline__ void bil(int i, int& j0, int& j1, float& wa, float& wb) {
  if (i & 1) {
    j0 = i >> 1; j1 = j0 + 1; wa = 0.75f; wb = 0.25f;
    if (j1 > 31) { j1 = 31; wa = 1.f; wb = 0.f; }
  } else {
    j0 = (i >> 1) - 1; j1 = j0 + 1; wa = 0.25f; wb = 0.75f;
    if (j0 < 0) { j0 = 0; wa = 0.f; wb = 1.f; }
  }
}

// mid = lepe(x) + upsample(att), 2 channels/thread -> f16 pairs
// midh[(b*64+c2)*4096 + p]
__global__ void k_mid(const float* __restrict__ x, const float* __restrict__ lepe_w,
                      const float* __restrict__ lepe_b, const float* __restrict__ att,
                      unsigned* __restrict__ midh) {
  int t = blockIdx.x * 256 + threadIdx.x;
  if (t >= NB * 64 * NH * NW) return;
  int p = t & 4095;
  int w = p & 63;
  int h0 = p >> 6;
  int bc2 = t >> 12;
  int c2 = bc2 & 63, b = bc2 >> 6;

  int jh0, jh1, jw0, jw1;
  float wha, whb, wwa, wwb;
  bil(h0, jh0, jh1, wha, whb);
  bil(w, jw0, jw1, wwa, wwb);

  float o[2];
#pragma unroll
  for (int j = 0; j < 2; j++) {
    int c = 2 * c2 + j;
    const float* xp = x + ((size_t)b * NC + c) * (NH * NW);
    const float* wp = lepe_w + c * 25;
    float acc = lepe_b[c];
#pragma unroll
    for (int ky = 0; ky < 5; ky++) {
      int ih = h0 + ky - 2;
      if (ih < 0 || ih > 63) continue;
#pragma unroll
      for (int kx = 0; kx < 5; kx++) {
        int iw = w + kx - 2;
        if (iw < 0 || iw > 63) continue;
        acc = fmaf(wp[ky * 5 + kx], xp[ih * 64 + iw], acc);
      }
    }
    const float* ap = att + ((size_t)b * NC + c) * NTOK;
    float up = wha * (wwa * ap[jh0 * 32 + jw0] + wwb * ap[jh0 * 32 + jw1]) +
               whb * (wwa * ap[jh1 * 32 + jw0] + wwb * ap[jh1 * 32 + jw1]);
    o[j] = acc + up;
  }
  midh[t] = pkf16(o[0], o[1]);
}

// ---------------------------------------------------------------
// final 1x1 conv via f16-dot2, 64 outputs per thread
__global__ void k_final(const unsigned* __restrict__ midh, const unsigned* __restrict__ wph,
                        const float* __restrict__ bias, float* __restrict__ out) {
  int p = (blockIdx.x & 15) * 256 + threadIdx.x;
  int rest = blockIdx.x >> 4;
  int cg = rest & 1;
  int b = rest >> 1;
  if (b >= NB) return;
  const unsigned* mp = midh + (size_t)b * 64 * 4096 + p;
  const unsigned* wp = wph + 24576 + cg * 64 * 64; // outh base
  float acc[64];
#pragma unroll
  for (int i = 0; i < 64; i++) acc[i] = bias[cg * 64 + i];
  for (int ci2 = 0; ci2 < 64; ci2++) {
    unsigned mv = mp[ci2 * 4096];
#pragma unroll
    for (int i = 0; i < 64; i++) acc[i] = fdot2(mv, wp[i * 64 + ci2], acc[i]);
  }
#pragma unroll
  for (int i = 0; i < 64; i++) out[((size_t)b * NC + cg * 64 + i) * 4096 + p] = acc[i];
}

// ---------------------------------------------------------------
extern "C" void kernel_launch(void* const* d_in, const int* in_sizes, int n_in,
                              void* d_out, int out_size, void* d_ws, size_t ws_size,
                              hipStream_t stream) {
  const float* x      = (const float*)d_in[0];
  const float* y      = (const float*)d_in[1];
  const float* rel    = (const float*)d_in[2];
  const float* q1_w   = (const float*)d_in[3];
  const float* q1_b   = (const float*)d_in[4];
  const float* q2_w   = (const float*)d_in[5];
  const float* q2_b   = (const float*)d_in[6];
  const float* kv1_w  = (const float*)d_in[7];
  const float* kv1_b  = (const float*)d_in[8];
  const float* kv2_w  = (const float*)d_in[9];
  const float* kv2_b  = (const float*)d_in[10];
  const float* lepe_w = (const float*)d_in[11];
  const float* lepe_b = (const float*)d_in[12];
  const float* out_w  = (const float*)d_in[13];
  const float* out_b  = (const float*)d_in[14];
  const float* temp   = (const float*)d_in[15];
  float* out = (float*)d_out;

  float* ws = (float*)d_ws;
  const size_t SP = (size_t)NB * NC * NTOK;   // 1,048,576
  float* attb = ws;                                        // SP f32
  unsigned* xph   = (unsigned*)(attb + SP);                // 512K u32
  unsigned* yph   = xph + 524288;                          // 512K u32
  unsigned* midh  = yph + 524288;                          // 2M u32
  unsigned* qh    = midh + 2097152;                        // 512K u32
  unsigned* kpair = qh + 524288;                           // 512K u32
  unsigned short* vbf = (unsigned short*)(kpair + 524288); // SP ushorts
  unsigned* wph   = (unsigned*)(vbf + SP);                 // 32768 u32

  k_pack<<<128, 256, 0, stream>>>(q1_w, kv1_w, out_w, wph);
  k_pool<<<4096, 256, 0, stream>>>(x, y, xph, yph);
  k_qpath<<<256, 1024, 0, stream>>>(xph, wph, q1_b, q2_w, q2_b, qh);
  k_kvpath<<<512, 1024, 0, stream>>>(yph, wph, kv1_b, kv2_w, kv2_b, kpair, vbf);
  k_attn<<<2048, 512, 0, stream>>>(qh, kpair, vbf, rel, temp, attb);
  k_mid<<<8192, 256, 0, stream>>>(x, lepe_w, lepe_b, attb, midh);
  k_final<<<256, 256, 0, stream>>>(midh, wph, out_b, out);
}

// Round 16
// 161.757 us; speedup vs baseline: 1.8966x; 1.3730x over previous
//
#include <hip/hip_runtime.h>

// Problem constants
#define NB 8
#define NC 128
#define NH 64
#define NW 64
#define HEADS 4
#define HP 32
#define WP 32
#define NTOK 1024     // HP*WP
#define TOPK 32
#define HDIM 32

typedef __fp16 hh2 __attribute__((ext_vector_type(2)));

__device__ __forceinline__ hh2 h2cast(unsigned u) {
  union { unsigned u; hh2 h; } x; x.u = u; return x.h;
}
__device__ __forceinline__ unsigned pkf16(float a, float b) {
  union { hh2 h; unsigned u; } x; x.h = __builtin_amdgcn_cvt_pkrtz(a, b); return x.u;
}

#if __has_builtin(__builtin_amdgcn_fdot2)
__device__ __forceinline__ float fdot2(unsigned kw, unsigned qw, float c) {
  return __builtin_amdgcn_fdot2(h2cast(kw), h2cast(qw), c, false);
}
#else
__device__ __forceinline__ float fdot2(unsigned kw, unsigned qw, float c) {
  hh2 k = h2cast(kw), q = h2cast(qw);
  return fmaf((float)k.x, (float)q.x, fmaf((float)k.y, (float)q.y, c));
}
#endif

// monotone float->uint map (order-preserving) and inverse
__device__ __forceinline__ unsigned fmap(float f) {
  unsigned u = __float_as_uint(f);
  return u ^ ((unsigned)((int)u >> 31) | 0x80000000u);
}
__device__ __forceinline__ float funmap(unsigned k) {
  unsigned uo = k ^ ((unsigned)((int)(~k) >> 31) | 0x80000000u);
  return __uint_as_float(uo);
}

// DPP wave64 max-reduce on unsigned; result broadcast via readlane(63)
__device__ __forceinline__ unsigned wave_maxu(unsigned v) {
#define ST(ctrl)                                                                     \
  {                                                                                  \
    unsigned o = (unsigned)__builtin_amdgcn_update_dpp(0, (int)v, ctrl, 0xF, 0xF, true); \
    v = v > o ? v : o;                                                               \
  }
  ST(0xB1)   // quad_perm [1,0,3,2]
  ST(0x4E)   // quad_perm [2,3,0,1]
  ST(0x141)  // row_half_mirror
  ST(0x140)  // row_mirror
  ST(0x142)  // row_bcast:15
  ST(0x143)  // row_bcast:31
#undef ST
  return (unsigned)__builtin_amdgcn_readlane((int)v, 63);
}

// DPP wave64 float sum-reduce; result broadcast via readlane(63)
__device__ __forceinline__ float wave_sumf(float v) {
#define STA(ctrl)                                                                    \
  v += __int_as_float(__builtin_amdgcn_update_dpp(0, __float_as_int(v), ctrl, 0xF, 0xF, true));
  STA(0xB1)
  STA(0x4E)
  STA(0x141)
  STA(0x140)
  STA(0x142)
  STA(0x143)
#undef STA
  return __int_as_float(__builtin_amdgcn_readlane(__float_as_int(v), 63));
}

// DPP wave64 inclusive prefix-sum on unsigned. Safe for packed 16+16 fields.
__device__ __forceinline__ unsigned wave_iprefix(unsigned v, int lane) {
#define SH(ctrl)                                                                     \
  v += (unsigned)__builtin_amdgcn_update_dpp(0, (int)v, ctrl, 0xF, 0xF, true);
  SH(0x111)  // row_shr:1
  SH(0x112)  // row_shr:2
  SH(0x114)  // row_shr:4
  SH(0x118)  // row_shr:8
#undef SH
  unsigned r0 = (unsigned)__builtin_amdgcn_readlane((int)v, 15);
  unsigned r1 = (unsigned)__builtin_amdgcn_readlane((int)v, 31);
  unsigned r2 = (unsigned)__builtin_amdgcn_readlane((int)v, 47);
  v += (lane >= 16) ? r0 : 0u;
  v += (lane >= 32) ? r1 : 0u;
  v += (lane >= 48) ? r2 : 0u;
  return v;
}

// ---------------------------------------------------------------
// prep: avg-pool x,y -> f16 channel-pairs AND pack conv weights to f16 pairs.
// pool: idx < 2*524288 ; pack: next 32768 items.
__global__ void k_prep(const float* __restrict__ x, const float* __restrict__ y,
                       const float* __restrict__ q1w, const float* __restrict__ kv1w,
                       const float* __restrict__ outw,
                       unsigned* __restrict__ xph, unsigned* __restrict__ yph,
                       unsigned* __restrict__ wph) {
  int idx = blockIdx.x * 256 + threadIdx.x;
  const int total = NB * 64 * NTOK; // 524288 pairs per array
  if (idx < 2 * total) {
    bool isY = idx >= total;
    int i = isY ? idx - total : idx;
    int p = i & 1023;
    int pw = p & 31, ph = p >> 5;
    int bc2 = i >> 10;
    int c2 = bc2 & 63, b = bc2 >> 6;
    const float* s0 = (isY ? y : x) + (((size_t)b * NC + 2 * c2) * 64 + ph * 2) * 64 + pw * 2;
    const float* s1 = s0 + 4096;
    float v0 = 0.25f * (s0[0] + s0[1] + s0[64] + s0[65]);
    float v1 = 0.25f * (s1[0] + s1[1] + s1[64] + s1[65]);
    (isY ? yph : xph)[i] = pkf16(v0, v1);
  } else {
    int i = idx - 2 * total;
    if (i >= 32768) return;
    const float* src;
    int off;
    if (i < 8192) { src = q1w; off = i; }
    else if (i < 24576) { src = kv1w; off = i - 8192; }
    else { src = outw; off = i - 24576; }
    int co = off >> 6, ci2 = off & 63;
    wph[i] = pkf16(src[co * 128 + 2 * ci2], src[co * 128 + 2 * ci2 + 1]);
  }
}

// ---------------------------------------------------------------
// unified q/kv path: f16-dot2 1x1 conv (4 ch/thread) -> LDS tile -> 3x3
// (depthwise for q, grouped-2 for kv). grid = 8b x 96 units (32 q + 64 kv).
__launch_bounds__(1024, 2)
__global__ void k_qkv(const unsigned* __restrict__ xph, const unsigned* __restrict__ yph,
                      const unsigned* __restrict__ wph,
                      const float* __restrict__ q1b, const float* __restrict__ q2w,
                      const float* __restrict__ q2b,
                      const float* __restrict__ kv1b, const float* __restrict__ kv2w,
                      const float* __restrict__ kv2b,
                      unsigned* __restrict__ qh, unsigned* __restrict__ kpair,
                      unsigned short* __restrict__ vbf) {
  __shared__ float cls[4][1024];
  int px = threadIdx.x;
  int bid = blockIdx.x;
  int b = bid / 96;
  int u = bid - b * 96;
  bool isQ = u < 32;
  int q = isQ ? u : u - 32;

  const unsigned* ip = (isQ ? xph : yph) + (size_t)b * 64 * NTOK + px;
  const unsigned* wp = wph + (isQ ? 0 : 8192) + q * 4 * 64;
  const float* bb = isQ ? q1b : kv1b;
  float acc[4];
#pragma unroll
  for (int i = 0; i < 4; i++) acc[i] = bb[q * 4 + i];
  for (int ci2 = 0; ci2 < 64; ci2++) {
    unsigned mv = ip[ci2 * NTOK];
#pragma unroll
    for (int i = 0; i < 4; i++) acc[i] = fdot2(mv, wp[i * 64 + ci2], acc[i]);
  }
#pragma unroll
  for (int i = 0; i < 4; i++) cls[i][px] = acc[i];
  __syncthreads();
  int pw = px & 31, ph = px >> 5;

  if (isQ) {
    float aout[4];
#pragma unroll
    for (int i = 0; i < 4; i++) {
      int c = q * 4 + i;
      const float* wq = q2w + c * 9;
      float a = q2b[c];
#pragma unroll
      for (int ky = 0; ky < 3; ky++) {
        int ih = ph + ky - 1;
        if (ih < 0 || ih > 31) continue;
#pragma unroll
        for (int kx = 0; kx < 3; kx++) {
          int iw = pw + kx - 1;
          if (iw < 0 || iw > 31) continue;
          a = fmaf(wq[ky * 3 + kx], cls[i][ih * 32 + iw], a);
        }
      }
      aout[i] = a;
    }
    int h = q >> 3;
    int d2 = ((q * 4) & 31) >> 1;
    size_t base = (((size_t)b * HEADS + h) * NTOK + px) * 16;
    qh[base + d2] = pkf16(aout[0], aout[1]);
    qh[base + d2 + 1] = pkf16(aout[2], aout[3]);
  } else {
    float aout[4];
#pragma unroll
    for (int i = 0; i < 4; i++) {
      int o = q * 4 + i;       // kv channel 0..255
      int l0 = i & ~1;         // group's first input channel within the quad
      const float* wq = kv2w + o * 18; // [2][3][3]
      float a = kv2b[o];
#pragma unroll
      for (int ky = 0; ky < 3; ky++) {
        int ih = ph + ky - 1;
        if (ih < 0 || ih > 31) continue;
#pragma unroll
        for (int kx = 0; kx < 3; kx++) {
          int iw = pw + kx - 1;
          if (iw < 0 || iw > 31) continue;
          a = fmaf(wq[ky * 3 + kx], cls[l0][ih * 32 + iw], a);
          a = fmaf(wq[9 + ky * 3 + kx], cls[l0 + 1][ih * 32 + iw], a);
        }
      }
      aout[i] = a;
    }
    if (q < 32) {
      // K channels: quad = 4 consecutive d within head h
      int h = q >> 3;
      int d2 = ((q * 4) & 31) >> 1;
      size_t base = (((size_t)b * HEADS + h) * 16) * NTOK + px;
      kpair[base + (size_t)d2 * NTOK] = pkf16(aout[0], aout[1]);
      kpair[base + (size_t)(d2 + 1) * NTOK] = pkf16(aout[2], aout[3]);
    } else {
      // V channels
#pragma unroll
      for (int i = 0; i < 4; i++) {
        int c = q * 4 + i - 128;
        int h = c >> 5, d = c & 31;
        union { __fp16 h; unsigned short u; } cv;
        cv.h = (__fp16)aout[i];
        vbf[(((size_t)b * HEADS + h) * NTOK + px) * HDIM + d] = cv.u;
      }
    }
  }
}

// ---------------------------------------------------------------
// attention v10 (byte-identical logic to round 15): 2 rows/wave, f16 dot2 QK,
// early-exit bsearch top-32, compaction, parallel softmax + V gather.
__launch_bounds__(512, 2)
__global__ void k_attn(const unsigned* __restrict__ qh, const unsigned* __restrict__ kpair,
                       const unsigned short* __restrict__ vbf, const float* __restrict__ rel,
                       const float* __restrict__ temp, float* __restrict__ att) {
  __shared__ __align__(16) unsigned ksh[16384];  // f16 K pairs [d2][n], 64KB
  __shared__ __align__(16) unsigned cbuf[8 * 64]; // per-wave 32x(key,token), 2KB

  int bid = blockIdx.x;
  int chunk = bid & 63;
  int h = (bid >> 6) & 3;
  int b = bid >> 8;
  int tid = threadIdx.x;
  int lane = tid & 63;
  int wave = __builtin_amdgcn_readfirstlane(tid >> 6); // 0..7, uniform

  // stage K pairs: 16384 u32 = 8192 uint2, 512 threads x 16
  const uint2* kg = (const uint2*)(kpair + ((size_t)b * HEADS + h) * 16 * NTOK);
  uint2* kl = (uint2*)ksh;
#pragma unroll
  for (int i = 0; i < 16; i++) kl[tid + i * 512] = kg[tid + i * 512];
  __syncthreads();

  const float tmpr = temp[h];
  const unsigned short* vb = vbf + ((size_t)(b * HEADS + h)) * NTOK * HDIM;
  int vlane = lane & 31;
  unsigned* row_lds = cbuf + wave * 64; // 32 entries x 8B, private per wave

  int qbase = chunk * 16 + wave * 2;

  // load q pairs for both rows (wave-uniform broadcast loads)
  unsigned qp[2][16];
#pragma unroll
  for (int r = 0; r < 2; r++) {
    const uint4* q4 = (const uint4*)(qh + (((size_t)b * HEADS + h) * NTOK + qbase + r) * 16);
#pragma unroll
    for (int i = 0; i < 4; i++) {
      uint4 t = q4[i];
      qp[r][i * 4 + 0] = t.x;
      qp[r][i * 4 + 1] = t.y;
      qp[r][i * 4 + 2] = t.z;
      qp[r][i * 4 + 3] = t.w;
    }
  }

  // logits via f16 dot2: acc[r][e] += K[d2](tok) . q[r][d2]
  float acc[2][16];
#pragma unroll
  for (int r = 0; r < 2; r++)
#pragma unroll
    for (int e = 0; e < 16; e++) acc[r][e] = 0.f;

#pragma unroll 4
  for (int d2 = 0; d2 < 16; d2++) {
#pragma unroll
    for (int i = 0; i < 4; i++) {
      uint4 kw = *(const uint4*)&ksh[d2 * 1024 + i * 256 + lane * 4]; // tokens i*256+lane*4+m
      acc[0][i * 4 + 0] = fdot2(kw.x, qp[0][d2], acc[0][i * 4 + 0]);
      acc[0][i * 4 + 1] = fdot2(kw.y, qp[0][d2], acc[0][i * 4 + 1]);
      acc[0][i * 4 + 2] = fdot2(kw.z, qp[0][d2], acc[0][i * 4 + 2]);
      acc[0][i * 4 + 3] = fdot2(kw.w, qp[0][d2], acc[0][i * 4 + 3]);
      acc[1][i * 4 + 0] = fdot2(kw.x, qp[1][d2], acc[1][i * 4 + 0]);
      acc[1][i * 4 + 1] = fdot2(kw.y, qp[1][d2], acc[1][i * 4 + 1]);
      acc[1][i * 4 + 2] = fdot2(kw.z, qp[1][d2], acc[1][i * 4 + 2]);
      acc[1][i * 4 + 3] = fdot2(kw.w, qp[1][d2], acc[1][i * 4 + 3]);
    }
  }

  // pack keys, fusing rel
  const float4* relp = (const float4*)(rel + (((size_t)b * HEADS + h) * NTOK + qbase) * NTOK);
  unsigned kk[2][16];
#pragma unroll
  for (int r = 0; r < 2; r++) {
#pragma unroll
    for (int i = 0; i < 4; i++) {
      float4 rv = relp[r * 256 + i * 64 + lane];
      kk[r][i * 4 + 0] = fmap(fmaf(tmpr, acc[r][i * 4 + 0], rv.x));
      kk[r][i * 4 + 1] = fmap(fmaf(tmpr, acc[r][i * 4 + 1], rv.y));
      kk[r][i * 4 + 2] = fmap(fmaf(tmpr, acc[r][i * 4 + 2], rv.z));
      kk[r][i * 4 + 3] = fmap(fmaf(tmpr, acc[r][i * 4 + 3], rv.w));
    }
  }

  // wave max per row (bsearch upper bound + softmax max)
  unsigned M[2];
#pragma unroll
  for (int r = 0; r < 2; r++) {
    unsigned mx = kk[r][0];
#pragma unroll
    for (int e = 1; e < 16; e++) mx = mx > kk[r][e] ? mx : kk[r][e];
    M[r] = wave_maxu(mx);
  }

  // early-exit binary search; cap 32 -> exact-tie fallback
  unsigned lo0 = 0u, hi0 = M[0], lo1 = 0u, hi1 = M[1];
  unsigned T0x = 0u, T1x = 0u;
  bool d0 = false, d1 = false;
#pragma unroll 1
  for (int it = 0; it < 32; it++) {
    if (d0 && d1) break;
    if (!d0) {
      unsigned mid = lo0 + ((hi0 - lo0) >> 1);
      int c = 0;
#pragma unroll
      for (int e = 0; e < 16; e++) c += (int)__popcll(__ballot(kk[0][e] > mid));
      if (c >= TOPK) lo0 = mid; else hi0 = mid;
      if (c == TOPK) { T0x = mid; d0 = true; }
    }
    if (!d1) {
      unsigned mid = lo1 + ((hi1 - lo1) >> 1);
      int c = 0;
#pragma unroll
      for (int e = 0; e < 16; e++) c += (int)__popcll(__ballot(kk[1][e] > mid));
      if (c >= TOPK) lo1 = mid; else hi1 = mid;
      if (c == TOPK) { T1x = mid; d1 = true; }
    }
  }
  unsigned T[2];
  T[0] = d0 ? T0x : hi0;
  T[1] = d1 ? T1x : hi1;

  // per-row: tie handling, compaction, softmax + V gather
#pragma unroll
  for (int r = 0; r < 2; r++) {
    unsigned gtc = 0, tq = 0;
#pragma unroll
    for (int e = 0; e < 16; e++) {
      gtc += (kk[r][e] > T[r]) ? 1u : 0u;
      tq += (kk[r][e] == T[r]) ? 1u : 0u;
    }
    unsigned packed = gtc | (tq << 16);
    unsigned incl = wave_iprefix(packed, lane);
    unsigned tot = (unsigned)__builtin_amdgcn_readlane((int)incl, 63);
    unsigned n_gt = tot & 0xFFFFu;
    unsigned tie_pfx = (incl >> 16) - tq;
    unsigned extras = (unsigned)TOPK - n_gt; // 0 on early-exit rows
    int el = (int)extras - (int)tie_pfx;
    el = el < 0 ? 0 : el;
    el = el > (int)tq ? (int)tq : el;
    unsigned sc = gtc + (unsigned)el;
    unsigned wbase = wave_iprefix(sc, lane) - sc;

    unsigned wp = wbase, tr = tie_pfx;
#pragma unroll
    for (int e = 0; e < 16; e++) {
      bool gt = kk[r][e] > T[r];
      bool eq = (kk[r][e] == T[r]);
      bool take = gt || (eq && (tr < extras));
      tr += eq ? 1u : 0u;
      if (take) {
        ((uint2*)row_lds)[wp] = make_uint2(kk[r][e], (unsigned)((e >> 2) * 256 + lane * 4 + (e & 3)));
        wp++;
      }
    }

    // parallel softmax over the 32 entries (lanes 0..31) + pipelined V gather
    uint2 ent = ((const uint2*)row_lds)[vlane];
    float fv = funmap(ent.x);
    float mv = funmap(M[r]);
    float e_ = __expf(fv - mv);
    e_ = (lane < TOPK) ? e_ : 0.f;
    float se = wave_sumf(e_);

    float oacc = 0.f;
#pragma unroll
    for (int t = 0; t < TOPK; t++) {
      float es = __int_as_float(__builtin_amdgcn_readlane(__float_as_int(e_), t));
      int tok = __builtin_amdgcn_readlane((int)ent.y, t);
      union { unsigned short u; __fp16 h; } cv;
      cv.u = vb[(size_t)tok * HDIM + vlane];
      oacc = fmaf(es, (float)cv.h, oacc);
    }

    if (lane < HDIM) {
      att[((size_t)b * NC + h * HDIM + lane) * NTOK + (qbase + r)] = oacc / se;
    }
  }
}

// ---------------------------------------------------------------
// bilinear 2x upsample weights (jax scale_and_translate semantics)
__device__ __forceinline__ void bil(int i, int& j0, int& j1, float& wa, float& wb) {
  if (i & 1) {
    j0 = i >> 1; j1 = j0 + 1; wa = 0.75f; wb = 0.25f;
    if (j1 > 31) { j1 = 31; wa = 1.f; wb = 0.f; }
  } else {
    j0 = (i >> 1) - 1; j1 = j0 + 1; wa = 0.25f; wb = 0.75f;
    if (j0 < 0) { j0 = 0; wa = 0.f; wb = 1.f; }
  }
}

// ---------------------------------------------------------------
// fused mid+final: phase 1 computes lepe+upsample for all 128 channels of
// one 64-px output row into LDS (f16 pairs, padded [64][65]); phase 2 runs
// the final 1x1 conv (f16-dot2, scalar-hoisted weights) from LDS.
// grid: 512 = 8b x 64 rows; block 256.
__launch_bounds__(256, 4)
__global__ void k_midfinal(const float* __restrict__ x, const float* __restrict__ lepe_w,
                           const float* __restrict__ lepe_b, const float* __restrict__ attb,
                           const unsigned* __restrict__ wph, const float* __restrict__ outb,
                           float* __restrict__ out) {
  __shared__ unsigned mlds[64 * 65]; // [ci2][px], +1 pad -> 2-way banks (free)
  int bid = blockIdx.x;
  int h0 = bid & 63;
  int b = bid >> 6;
  int t = threadIdx.x;
  int ci2 = t >> 2;
  int w0 = (t & 3) * 16;

  int jh0, jh1;
  float wha, whb;
  bil(h0, jh0, jh1, wha, whb);

  float o0[16], o1[16];
#pragma unroll
  for (int cc = 0; cc < 2; cc++) {
    int c = 2 * ci2 + cc;
    const float* xp = x + ((size_t)b * NC + c) * 4096;
    const float* wq = lepe_w + c * 25;
    float* o = cc ? o1 : o0;
    float bv = lepe_b[c];
#pragma unroll
    for (int j = 0; j < 16; j++) o[j] = bv;
#pragma unroll
    for (int ky = 0; ky < 5; ky++) {
      int ih = h0 + ky - 2;
      if (ih < 0 || ih > 63) continue;
      float xr[20]; // sliding window [w0-2 .. w0+17]
#pragma unroll
      for (int m = 0; m < 20; m++) {
        int iw = w0 + m - 2;
        xr[m] = (iw >= 0 && iw <= 63) ? xp[ih * 64 + iw] : 0.f;
      }
#pragma unroll
      for (int kx = 0; kx < 5; kx++) {
        float wv = wq[ky * 5 + kx];
#pragma unroll
        for (int j = 0; j < 16; j++) o[j] = fmaf(wv, xr[j + kx], o[j]);
      }
    }
    // upsample add
    const float* ap = attb + ((size_t)b * NC + c) * NTOK;
#pragma unroll
    for (int j = 0; j < 16; j++) {
      int w = w0 + j;
      int jw0, jw1;
      float wwa, wwb;
      bil(w, jw0, jw1, wwa, wwb);
      float up = wha * (wwa * ap[jh0 * 32 + jw0] + wwb * ap[jh0 * 32 + jw1]) +
                 whb * (wwa * ap[jh1 * 32 + jw0] + wwb * ap[jh1 * 32 + jw1]);
      o[j] += up;
    }
  }
#pragma unroll
  for (int j = 0; j < 16; j++) mlds[ci2 * 65 + w0 + j] = pkf16(o0[j], o1[j]);
  __syncthreads();

  // phase 2: final 1x1, 32 outputs/thread
  int px = t & 63;
  int cg = __builtin_amdgcn_readfirstlane(t >> 6); // wave-uniform -> s_loads
  float acc[32];
#pragma unroll
  for (int i = 0; i < 32; i++) acc[i] = outb[cg * 32 + i];
  const unsigned* wpf = wph + 24576 + (size_t)cg * 32 * 64;
  for (int ci = 0; ci < 64; ci++) {
    unsigned mv = mlds[ci * 65 + px];
#pragma unroll
    for (int i = 0; i < 32; i++) acc[i] = fdot2(mv, wpf[i * 64 + ci], acc[i]);
  }
#pragma unroll
  for (int i = 0; i < 32; i++)
    out[((size_t)b * NC + cg * 32 + i) * 4096 + h0 * 64 + px] = acc[i];
}

// ---------------------------------------------------------------
extern "C" void kernel_launch(void* const* d_in, const int* in_sizes, int n_in,
                              void* d_out, int out_size, void* d_ws, size_t ws_size,
                              hipStream_t stream) {
  const float* x      = (const float*)d_in[0];
  const float* y      = (const float*)d_in[1];
  const float* rel    = (const float*)d_in[2];
  const float* q1_w   = (const float*)d_in[3];
  const float* q1_b   = (const float*)d_in[4];
  const float* q2_w   = (const float*)d_in[5];
  const float* q2_b   = (const float*)d_in[6];
  const float* kv1_w  = (const float*)d_in[7];
  const float* kv1_b  = (const float*)d_in[8];
  const float* kv2_w  = (const float*)d_in[9];
  const float* kv2_b  = (const float*)d_in[10];
  const float* lepe_w = (const float*)d_in[11];
  const float* lepe_b = (const float*)d_in[12];
  const float* out_w  = (const float*)d_in[13];
  const float* out_b  = (const float*)d_in[14];
  const float* temp   = (const float*)d_in[15];
  float* out = (float*)d_out;

  float* ws = (float*)d_ws;
  const size_t SP = (size_t)NB * NC * NTOK;   // 1,048,576
  float* attb = ws;                                        // SP f32 (4MB)
  unsigned* xph   = (unsigned*)(attb + SP);                // 512K u32 (2MB)
  unsigned* yph   = xph + 524288;                          // 512K u32 (2MB)
  unsigned* qh    = yph + 524288;                          // 512K u32 (2MB)
  unsigned* kpair = qh + 524288;                           // 512K u32 (2MB)
  unsigned short* vbf = (unsigned short*)(kpair + 524288); // SP ushorts (2MB)
  unsigned* wph   = (unsigned*)(vbf + SP);                 // 32768 u32 (128KB)

  k_prep<<<4224, 256, 0, stream>>>(x, y, q1_w, kv1_w, out_w, xph, yph, wph);
  k_qkv<<<768, 1024, 0, stream>>>(xph, yph, wph, q1_b, q2_w, q2_b,
                                  kv1_b, kv2_w, kv2_b, qh, kpair, vbf);
  k_attn<<<2048, 512, 0, stream>>>(qh, kpair, vbf, rel, temp, attb);
  k_midfinal<<<512, 256, 0, stream>>>(x, lepe_w, lepe_b, attb, wph, out_b, out);
}